// Round 2
// baseline (74.913 us; speedup 1.0000x reference)
//
#include <hip/hip_runtime.h>
#include <math.h>

#define NP 16
#define TOTAL 5776
#define NB 8192
#define NBLK 2048       // 4 samples (waves) per block
#define EPS 0.1f
#define MAXK 10         // 640 / 64

__device__ __constant__ int d_counts[NP] = {128,256,512,384,192,640,320,448,256,512,128,384,576,320,448,256};
__device__ __constant__ int d_starts[NP] = {0,128,384,896,1280,1472,2112,2432,2880,3136,3648,3776,4160,4736,5056,5504};

// ws layout: [0] unsigned counter (zeroed by memset node each replay);
//            [64..64+NBLK) float block partials
__global__ __launch_bounds__(256) void mlce_fused_kernel(
        const float* __restrict__ predicts,
        const int* __restrict__ parent_t,
        const int* __restrict__ child_t,
        float* __restrict__ out,
        unsigned* __restrict__ cnt,
        float* __restrict__ partials)
{
    __shared__ float sdata[4];
    __shared__ unsigned is_last;

    const int wave = threadIdx.x >> 6;
    const int lane = threadIdx.x & 63;
    const int b = (blockIdx.x << 2) + wave;   // always < NB (2048*4 == 8192)

    const float* __restrict__ row = predicts + (size_t)b * TOTAL;
    const int p = parent_t[b];
    const int t = child_t[b];
    const int c = d_counts[p];   // multiple of 64 -> wave-uniform
    const int s = d_starts[p];
    const float* __restrict__ ch = row + NP + s;

    // ---- child range: registers, static indices ----
    float v[MAXK];
    float vmax = -INFINITY;
#pragma unroll
    for (int k = 0; k < MAXK; ++k) {
        const int j = lane + (k << 6);
        v[k] = (j < c) ? ch[j] : -INFINITY;
        vmax = fmaxf(vmax, v[k]);
    }
#pragma unroll
    for (int off = 32; off; off >>= 1) vmax = fmaxf(vmax, __shfl_xor(vmax, off));

    float se = 0.f, sx = 0.f;
#pragma unroll
    for (int k = 0; k < MAXK; ++k) {
        const int j = lane + (k << 6);
        if (j < c) { se += __expf(v[k] - vmax); sx += v[k]; }
    }
#pragma unroll
    for (int off = 32; off; off >>= 1) {
        se += __shfl_xor(se, off);
        sx += __shfl_xor(sx, off);
    }

    // ---- parent softmax over 16 logits ----
    const float pv = (lane < NP) ? row[lane] : -INFINITY;
    float pmax = pv;
#pragma unroll
    for (int off = 32; off; off >>= 1) pmax = fmaxf(pmax, __shfl_xor(pmax, off));
    float pse = (lane < NP) ? __expf(pv - pmax) : 0.f;
    float psx = (lane < NP) ? pv : 0.f;
#pragma unroll
    for (int off = 32; off; off >>= 1) {
        pse += __shfl_xor(pse, off);
        psx += __shfl_xor(psx, off);
    }

    // targets already resident in registers: no dependent global load
    const float xt  = __shfl((t & 64) ? v[1] : v[0], t & 63);  // t < 128 <= c
    const float xpt = __shfl(pv, p);                            // p < 16

    float wloss = 0.f;
    if (lane == 0) {
        const float logZc = __logf(se);
        const float loss_c = -(1.f - EPS) * (xt - vmax - logZc)
                             - (EPS / (float)c) * sx
                             + EPS * (vmax + logZc);
        const float logZp = __logf(pse);
        const float loss_p = -(1.f - EPS) * (xpt - pmax - logZp)
                             - (EPS / (float)NP) * psx
                             + EPS * (pmax + logZp);
        wloss = loss_c + loss_p;
    }

    if (lane == 0) sdata[wave] = wloss;
    __syncthreads();

    if (threadIdx.x == 0) {
        const float bpart = sdata[0] + sdata[1] + sdata[2] + sdata[3];
        partials[blockIdx.x] = bpart;
        __threadfence();  // device-scope: flush partial past this XCD's L2
        const unsigned old = __hip_atomic_fetch_add(cnt, 1u, __ATOMIC_ACQ_REL,
                                                    __HIP_MEMORY_SCOPE_AGENT);
        is_last = (old == NBLK - 1) ? 1u : 0u;
    }
    __syncthreads();

    if (is_last) {
        // fixed-order deterministic final sum of NBLK partials
        float sum = 0.f;
#pragma unroll
        for (int i = 0; i < NBLK / 256; ++i) {
            sum += __hip_atomic_load(&partials[threadIdx.x + (i << 8)],
                                     __ATOMIC_RELAXED, __HIP_MEMORY_SCOPE_AGENT);
        }
#pragma unroll
        for (int off = 32; off; off >>= 1) sum += __shfl_xor(sum, off);
        __syncthreads();                 // sdata reuse
        if (lane == 0) sdata[wave] = sum;
        __syncthreads();
        if (threadIdx.x == 0) {
            out[0] = (sdata[0] + sdata[1] + sdata[2] + sdata[3]) * (1.f / (float)NB);
        }
    }
}

extern "C" void kernel_launch(void* const* d_in, const int* in_sizes, int n_in,
                              void* d_out, int out_size, void* d_ws, size_t ws_size,
                              hipStream_t stream)
{
    const float* predicts = (const float*)d_in[0];
    const int*   parent_t = (const int*)d_in[1];
    const int*   child_t  = (const int*)d_in[2];
    float* out = (float*)d_out;
    unsigned* cnt = (unsigned*)d_ws;
    float* partials = (float*)d_ws + 64;

    hipMemsetAsync(d_ws, 0, 256, stream);  // reset counter each replay (graph node)
    mlce_fused_kernel<<<NBLK, 256, 0, stream>>>(predicts, parent_t, child_t,
                                                out, cnt, partials);
}

// Round 3
// 11.903 us; speedup vs baseline: 6.2934x; 6.2934x over previous
//
#include <hip/hip_runtime.h>
#include <math.h>

#define NP 16
#define TOTAL 5776
#define NB 8192
#define NBLK 2048       // 4 samples (one wave each) per block
#define EPS 0.1f
#define MAXK4 3         // 640/4 = 160 float4 lanes -> 3 chunks of 64

__device__ __constant__ int d_counts[NP] = {128,256,512,384,192,640,320,448,256,512,128,384,576,320,448,256};
__device__ __constant__ int d_starts[NP] = {0,128,384,896,1280,1472,2112,2432,2880,3136,3648,3776,4160,4736,5056,5504};

// One wave per sample; 4 waves per block; per-block partial out.
__global__ __launch_bounds__(256) void mlce_sample_kernel(
        const float* __restrict__ predicts,
        const int* __restrict__ parent_t,
        const int* __restrict__ child_t,
        float* __restrict__ partials)
{
    __shared__ float sdata[4];
    const int wave = threadIdx.x >> 6;
    const int lane = threadIdx.x & 63;
    const int b = (blockIdx.x << 2) + wave;        // < NB always

    const float* __restrict__ row = predicts + (size_t)b * TOTAL;
    const int p = parent_t[b];
    const int t = child_t[b];
    const int c = d_counts[p];                     // multiple of 64, wave-uniform
    const int s = d_starts[p];
    const float* __restrict__ ch = row + NP + s;   // 16B aligned (all offsets %4==0)
    const float4* __restrict__ ch4 = (const float4*)ch;
    const int c4 = c >> 2;                         // multiple of 16, <= 160

    // ---- child range: <=3 float4 loads per lane ----
    float4 v[MAXK4];
    float vmax = -INFINITY;
#pragma unroll
    for (int k = 0; k < MAXK4; ++k) {
        const int j = lane + (k << 6);
        if (j < c4) {
            v[k] = ch4[j];
            vmax = fmaxf(fmaxf(vmax, fmaxf(v[k].x, v[k].y)), fmaxf(v[k].z, v[k].w));
        } else {
            v[k] = make_float4(-INFINITY, -INFINITY, -INFINITY, -INFINITY);
        }
    }
#pragma unroll
    for (int off = 32; off; off >>= 1) vmax = fmaxf(vmax, __shfl_xor(vmax, off));

    float se = 0.f, sx = 0.f;
#pragma unroll
    for (int k = 0; k < MAXK4; ++k) {
        const int j = lane + (k << 6);
        if (j < c4) {
            se += __expf(v[k].x - vmax) + __expf(v[k].y - vmax)
                + __expf(v[k].z - vmax) + __expf(v[k].w - vmax);
            sx += v[k].x + v[k].y + v[k].z + v[k].w;
        }
    }
#pragma unroll
    for (int off = 32; off; off >>= 1) {
        se += __shfl_xor(se, off);
        sx += __shfl_xor(sx, off);
    }

    // ---- parent softmax over 16 logits ----
    const float pv = (lane < NP) ? row[lane] : -INFINITY;
    float pmax = pv;
#pragma unroll
    for (int off = 32; off; off >>= 1) pmax = fmaxf(pmax, __shfl_xor(pmax, off));
    float pse = (lane < NP) ? __expf(pv - pmax) : 0.f;
    float psx = (lane < NP) ? pv : 0.f;
#pragma unroll
    for (int off = 32; off; off >>= 1) {
        pse += __shfl_xor(pse, off);
        psx += __shfl_xor(psx, off);
    }

    // targets from registers (t < 128 -> chunk 0, lane t>>2, comp t&3)
    const float selc = (t & 2) ? ((t & 1) ? v[0].w : v[0].z)
                               : ((t & 1) ? v[0].y : v[0].x);
    const float xt  = __shfl(selc, t >> 2);
    const float xpt = __shfl(pv, p);

    float wloss = 0.f;
    if (lane == 0) {
        const float logZc = __logf(se);
        const float loss_c = -(1.f - EPS) * (xt - vmax - logZc)
                             - (EPS / (float)c) * sx
                             + EPS * (vmax + logZc);
        const float logZp = __logf(pse);
        const float loss_p = -(1.f - EPS) * (xpt - pmax - logZp)
                             - (EPS / (float)NP) * psx
                             + EPS * (pmax + logZp);
        wloss = loss_c + loss_p;
    }
    if (lane == 0) sdata[wave] = wloss;
    __syncthreads();
    if (threadIdx.x == 0)
        partials[blockIdx.x] = sdata[0] + sdata[1] + sdata[2] + sdata[3];
}

// Deterministic single-block reduction of NBLK per-block partials.
__global__ __launch_bounds__(256) void mlce_reduce_kernel(
        const float* __restrict__ partials, float* __restrict__ out)
{
    __shared__ float sdata[4];
    const float4* __restrict__ p4 = (const float4*)partials;   // 512 float4s
    const float4 a = p4[threadIdx.x];
    const float4 bb = p4[threadIdx.x + 256];
    float sum = ((a.x + a.y) + (a.z + a.w)) + ((bb.x + bb.y) + (bb.z + bb.w));
#pragma unroll
    for (int off = 32; off; off >>= 1) sum += __shfl_xor(sum, off);
    const int wave = threadIdx.x >> 6;
    const int lane = threadIdx.x & 63;
    if (lane == 0) sdata[wave] = sum;
    __syncthreads();
    if (threadIdx.x == 0)
        out[0] = (sdata[0] + sdata[1] + sdata[2] + sdata[3]) * (1.f / (float)NB);
}

extern "C" void kernel_launch(void* const* d_in, const int* in_sizes, int n_in,
                              void* d_out, int out_size, void* d_ws, size_t ws_size,
                              hipStream_t stream)
{
    const float* predicts = (const float*)d_in[0];
    const int*   parent_t = (const int*)d_in[1];
    const int*   child_t  = (const int*)d_in[2];
    float* out = (float*)d_out;
    float* partials = (float*)d_ws;   // 2048 floats, fully rewritten every call

    mlce_sample_kernel<<<NBLK, 256, 0, stream>>>(predicts, parent_t, child_t, partials);
    mlce_reduce_kernel<<<1, 256, 0, stream>>>(partials, out);
}

// Round 4
// 11.768 us; speedup vs baseline: 6.3657x; 1.0115x over previous
//
#include <hip/hip_runtime.h>
#include <math.h>

#define NP 16
#define TOTAL 5776
#define NB 8192
#define NBLK 1024       // 8 samples (one wave each) per block of 512 threads
#define EPS 0.1f
#define MAXK4 3         // 640/4 = 160 float4 lanes -> 3 chunks of 64

__device__ __constant__ int d_counts[NP] = {128,256,512,384,192,640,320,448,256,512,128,384,576,320,448,256};
__device__ __constant__ int d_starts[NP] = {0,128,384,896,1280,1472,2112,2432,2880,3136,3648,3776,4160,4736,5056,5504};

// One wave per sample; 8 waves per block; per-block partial out.
__global__ __launch_bounds__(512, 8) void mlce_sample_kernel(
        const float* __restrict__ predicts,
        const int* __restrict__ parent_t,
        const int* __restrict__ child_t,
        float* __restrict__ partials)
{
    __shared__ float sdata[8];
    const int wave = threadIdx.x >> 6;
    const int lane = threadIdx.x & 63;
    const int b = (blockIdx.x << 3) + wave;        // < NB always (1024*8 == 8192)

    const float* __restrict__ row = predicts + (size_t)b * TOTAL;
    const int p = parent_t[b];                     // wave-uniform -> s_load
    const int t = child_t[b];
    const int c = d_counts[p];                     // multiple of 64, wave-uniform
    const int s = d_starts[p];
    const float* __restrict__ ch = row + NP + s;   // 16B aligned
    const float4* __restrict__ ch4 = (const float4*)ch;
    const int c4 = c >> 2;                         // multiple of 16, <= 160

    // ---- child range: <=3 float4 loads per lane ----
    float4 v[MAXK4];
    float vmax = -INFINITY;
#pragma unroll
    for (int k = 0; k < MAXK4; ++k) {
        const int j = lane + (k << 6);
        if (j < c4) {
            v[k] = ch4[j];
            vmax = fmaxf(fmaxf(vmax, fmaxf(v[k].x, v[k].y)), fmaxf(v[k].z, v[k].w));
        } else {
            v[k] = make_float4(-INFINITY, -INFINITY, -INFINITY, -INFINITY);
        }
    }
#pragma unroll
    for (int off = 32; off; off >>= 1) vmax = fmaxf(vmax, __shfl_xor(vmax, off));

    float se = 0.f, sx = 0.f;
#pragma unroll
    for (int k = 0; k < MAXK4; ++k) {
        const int j = lane + (k << 6);
        if (j < c4) {
            se += __expf(v[k].x - vmax) + __expf(v[k].y - vmax)
                + __expf(v[k].z - vmax) + __expf(v[k].w - vmax);
            sx += v[k].x + v[k].y + v[k].z + v[k].w;
        }
    }
#pragma unroll
    for (int off = 32; off; off >>= 1) {
        se += __shfl_xor(se, off);
        sx += __shfl_xor(sx, off);
    }

    // ---- parent softmax over 16 logits ----
    const float pv = (lane < NP) ? row[lane] : -INFINITY;
    float pmax = pv;
#pragma unroll
    for (int off = 32; off; off >>= 1) pmax = fmaxf(pmax, __shfl_xor(pmax, off));
    float pse = (lane < NP) ? __expf(pv - pmax) : 0.f;
    float psx = (lane < NP) ? pv : 0.f;
#pragma unroll
    for (int off = 32; off; off >>= 1) {
        pse += __shfl_xor(pse, off);
        psx += __shfl_xor(psx, off);
    }

    // targets from registers (t < 128 -> chunk 0, lane t>>2, comp t&3)
    const float selc = (t & 2) ? ((t & 1) ? v[0].w : v[0].z)
                               : ((t & 1) ? v[0].y : v[0].x);
    const float xt  = __shfl(selc, t >> 2);
    const float xpt = __shfl(pv, p);

    float wloss = 0.f;
    if (lane == 0) {
        const float logZc = __logf(se);
        const float loss_c = -(1.f - EPS) * (xt - vmax - logZc)
                             - (EPS / (float)c) * sx
                             + EPS * (vmax + logZc);
        const float logZp = __logf(pse);
        const float loss_p = -(1.f - EPS) * (xpt - pmax - logZp)
                             - (EPS / (float)NP) * psx
                             + EPS * (pmax + logZp);
        wloss = loss_c + loss_p;
    }
    if (lane == 0) sdata[wave] = wloss;
    __syncthreads();
    if (threadIdx.x == 0) {
        float bp = 0.f;
#pragma unroll
        for (int i = 0; i < 8; ++i) bp += sdata[i];
        partials[blockIdx.x] = bp;
    }
}

// Deterministic single-block reduction: 1024 partials, one float4 per lane.
__global__ __launch_bounds__(256) void mlce_reduce_kernel(
        const float* __restrict__ partials, float* __restrict__ out)
{
    __shared__ float sdata[4];
    const float4* __restrict__ p4 = (const float4*)partials;   // 256 float4s
    const float4 a = p4[threadIdx.x];
    float sum = (a.x + a.y) + (a.z + a.w);
#pragma unroll
    for (int off = 32; off; off >>= 1) sum += __shfl_xor(sum, off);
    const int wave = threadIdx.x >> 6;
    const int lane = threadIdx.x & 63;
    if (lane == 0) sdata[wave] = sum;
    __syncthreads();
    if (threadIdx.x == 0)
        out[0] = (sdata[0] + sdata[1] + sdata[2] + sdata[3]) * (1.f / (float)NB);
}

extern "C" void kernel_launch(void* const* d_in, const int* in_sizes, int n_in,
                              void* d_out, int out_size, void* d_ws, size_t ws_size,
                              hipStream_t stream)
{
    const float* predicts = (const float*)d_in[0];
    const int*   parent_t = (const int*)d_in[1];
    const int*   child_t  = (const int*)d_in[2];
    float* out = (float*)d_out;
    float* partials = (float*)d_ws;   // 1024 floats, fully rewritten every call

    mlce_sample_kernel<<<NBLK, 512, 0, stream>>>(predicts, parent_t, child_t, partials);
    mlce_reduce_kernel<<<1, 256, 0, stream>>>(partials, out);
}